// Round 4
// baseline (306.260 us; speedup 1.0000x reference)
//
#include <hip/hip_runtime.h>

// DirectNormLoss: B=16384 rows, D=2048 features, 1000 classes.
// loss = mean_i [ 1 - <s_i, c_i> / (||c_i|| * max(||s_i||, ||t_i||)) ]
//
// R8 = R7 re-run (container failed twice; infra, not kernel — audited for
// hangs: all barriers uniform, offsets[1000]=NROWS, deterministic output).
// Model: per-CU READ-path cap ~6 B/cyc (384MB logical / 256 CU / 252K cyc
// = 5.95 B/cyc; six structural variants invariant at 103-110us with HBM
// 22%, VALU 7%). Lever: cut logical read bytes. 120MB of 384MB is
// redundant center re-reads (~16.4 rows/label share one 8KB center).
//   Kernel A (1 blk x 1024): LDS histogram -> scan -> scatter row lists.
//   Kernel B (1000 blks x 256): stage center once (LDS->regs), waves loop
//     over that label's rows reading only s,t (16KB/row).
// Logical reads 384MB -> 264MB. Predict label kernel ~72-78us; falsified
// if it still runs ~105us.

#define NROWS  16384
#define DDIM   2048
#define NLAB   1000
#define BLK    256
#define WPB    (BLK / 64)          // 4 waves per block
#define GRID_AT (NROWS / WPB)      // fallback grid (wave/row)

typedef float v4f __attribute__((ext_vector_type(4)));

__device__ __forceinline__ float dot4(const v4f a, const v4f b) {
    return a.x*b.x + a.y*b.y + a.z*b.z + a.w*b.w;
}

// ---- Kernel A: build per-label row lists (single block, no global sync) ----
__global__ __launch_bounds__(1024) void dnl_hist_kernel(
    const int* __restrict__ labels,
    int*       __restrict__ offsets,   // [NLAB+1] exclusive starts
    int*       __restrict__ list)      // [NROWS] row indices grouped by label
{
    __shared__ int cnt[1024];
    __shared__ int cur[1024];
    const int tid = threadIdx.x;
    cnt[tid] = 0;
    __syncthreads();

    int myl[16];
    #pragma unroll
    for (int j = 0; j < 16; ++j)
        myl[j] = labels[tid + j * 1024];          // coalesced pass
    #pragma unroll
    for (int j = 0; j < 16; ++j)
        atomicAdd(&cnt[myl[j]], 1);
    __syncthreads();

    const int count_mine = cnt[tid];
    // Hillis-Steele inclusive scan over 1024 entries (labels < 1000).
    for (int off = 1; off < 1024; off <<= 1) {
        const int v = (tid >= off) ? cnt[tid - off] : 0;
        __syncthreads();
        cnt[tid] += v;
        __syncthreads();
    }
    const int start = cnt[tid] - count_mine;      // exclusive prefix
    cur[tid] = start;
    if (tid <= NLAB) offsets[tid] = start;        // tid==NLAB -> NROWS
    __syncthreads();

    #pragma unroll
    for (int j = 0; j < 16; ++j) {
        const int row  = tid + j * 1024;
        const int slot = atomicAdd(&cur[myl[j]], 1);
        list[slot] = row;
    }
}

// ---- Kernel B: one block per label; center read ONCE, rows share it ----
__global__ __launch_bounds__(BLK) void dnl_label_kernel(
    const float* __restrict__ s_emb,
    const float* __restrict__ t_emb,
    const float* __restrict__ T_EMB,
    const int*   __restrict__ offsets,
    const int*   __restrict__ list,
    float*       __restrict__ partial)   // [NROWS]
{
    const int tid   = threadIdx.x;
    const int lane  = tid & 63;
    const int wv    = tid >> 6;
    const int label = blockIdx.x;

    const int beg = offsets[label];
    const int end = offsets[label + 1];
    if (beg == end) return;               // block-uniform: safe early exit

    // Stage the 8KB center row once (coalesced), then lift to registers.
    __shared__ v4f cLds[512];
    const v4f* c4 = (const v4f*)(T_EMB + (size_t)label * DDIM);
    cLds[tid]       = c4[tid];
    cLds[tid + 256] = c4[tid + 256];
    __syncthreads();

    v4f c[8];
    #pragma unroll
    for (int j = 0; j < 8; ++j) c[j] = cLds[lane + j * 64];

    float cc = 0.f;
    #pragma unroll
    for (int j = 0; j < 8; ++j) cc += dot4(c[j], c[j]);
    #pragma unroll
    for (int off = 32; off > 0; off >>= 1) cc += __shfl_xor(cc, off, 64);
    const float cnorm = sqrtf(cc);

    // Waves split this label's rows; per row only s,t are read (16KB).
    for (int i = beg + wv; i < end; i += WPB) {
        const int row = list[i];
        const v4f* s4 = (const v4f*)(s_emb + (size_t)row * DDIM);
        const v4f* t4 = (const v4f*)(t_emb + (size_t)row * DDIM);

        float ss = 0.f, tt = 0.f, sc = 0.f;
        #pragma unroll
        for (int j = 0; j < 8; ++j) {
            const int k = lane + j * 64;
            const v4f s = s4[k];
            const v4f t = t4[k];
            ss += dot4(s, s);
            tt += dot4(t, t);
            sc += dot4(s, c[j]);
        }
        #pragma unroll
        for (int off = 32; off > 0; off >>= 1) {
            ss += __shfl_xor(ss, off, 64);
            tt += __shfl_xor(tt, off, 64);
            sc += __shfl_xor(sc, off, 64);
        }
        if (lane == 0) {
            const float max_norm = fmaxf(sqrtf(ss), sqrtf(tt));
            partial[row] = 1.0f - sc / (cnorm * max_norm);
        }
    }
}

__global__ __launch_bounds__(BLK) void dnl_reduce_kernel(
    const float* __restrict__ partial,
    float*       __restrict__ out)
{
    const int tid = threadIdx.x;
    const float4* p4 = (const float4*)partial;
    float sum = 0.f;
    #pragma unroll
    for (int j = 0; j < 16; ++j) {
        const float4 v = p4[tid + j * BLK];
        sum += v.x + v.y + v.z + v.w;
    }
    #pragma unroll
    for (int off = 32; off > 0; off >>= 1)
        sum += __shfl_xor(sum, off, 64);

    __shared__ float red[4];
    if ((tid & 63) == 0) red[tid >> 6] = sum;
    __syncthreads();
    if (tid == 0)
        out[0] = (red[0] + red[1] + red[2] + red[3]) * (1.0f / (float)NROWS);
}

// Atomic fallback (only if ws too small): wave/row, known-good ~107us path.
__global__ __launch_bounds__(BLK, 2) void dnl_main_atomic_kernel(
    const float* __restrict__ s_emb,
    const float* __restrict__ t_emb,
    const float* __restrict__ T_EMB,
    const int*   __restrict__ labels,
    float*       __restrict__ out)
{
    const int tid  = threadIdx.x;
    const int lane = tid & 63;
    const int row  = blockIdx.x * WPB + (tid >> 6);
    const int label = labels[row];

    const v4f* s4 = (const v4f*)(s_emb + (size_t)row   * DDIM);
    const v4f* t4 = (const v4f*)(t_emb + (size_t)row   * DDIM);
    const v4f* c4 = (const v4f*)(T_EMB + (size_t)label * DDIM);

    float ss = 0.f, tt = 0.f, sc = 0.f, cc = 0.f;
    #pragma unroll
    for (int j = 0; j < 8; ++j) {
        const int k = lane + j * 64;
        const v4f s = s4[k];
        const v4f t = t4[k];
        const v4f c = c4[k];
        ss += dot4(s, s);
        tt += dot4(t, t);
        sc += dot4(s, c);
        cc += dot4(c, c);
    }
    #pragma unroll
    for (int off = 32; off > 0; off >>= 1) {
        ss += __shfl_xor(ss, off, 64);
        tt += __shfl_xor(tt, off, 64);
        sc += __shfl_xor(sc, off, 64);
        cc += __shfl_xor(cc, off, 64);
    }
    if (lane == 0) {
        const float max_norm = fmaxf(sqrtf(ss), sqrtf(tt));
        atomicAdd(out, (1.0f - sc / (sqrtf(cc) * max_norm)) * (1.0f / (float)NROWS));
    }
}

extern "C" void kernel_launch(void* const* d_in, const int* in_sizes, int n_in,
                              void* d_out, int out_size, void* d_ws, size_t ws_size,
                              hipStream_t stream) {
    const float* s_emb  = (const float*)d_in[0];
    const float* t_emb  = (const float*)d_in[1];
    const float* T_EMB  = (const float*)d_in[2];
    const int*   labels = (const int*)d_in[3];
    float* out = (float*)d_out;

    // ws layout: [partial: NROWS f32][list: NROWS i32][offsets: NLAB+1 i32]
    const size_t need = (size_t)NROWS * 4 * 2 + (size_t)(NLAB + 1) * 4;

    if (ws_size >= need) {
        float* partial = (float*)d_ws;
        int*   list    = (int*)((char*)d_ws + (size_t)NROWS * 4);
        int*   offsets = (int*)((char*)d_ws + (size_t)NROWS * 8);
        dnl_hist_kernel<<<1, 1024, 0, stream>>>(labels, offsets, list);
        dnl_label_kernel<<<NLAB, BLK, 0, stream>>>(s_emb, t_emb, T_EMB,
                                                   offsets, list, partial);
        dnl_reduce_kernel<<<1, BLK, 0, stream>>>(partial, out);
    } else {
        hipMemsetAsync(d_out, 0, sizeof(float), stream);
        dnl_main_atomic_kernel<<<GRID_AT, BLK, 0, stream>>>(s_emb, t_emb, T_EMB, labels, out);
    }
}

// Round 5
// 282.695 us; speedup vs baseline: 1.0834x; 1.0834x over previous
//
#include <hip/hip_runtime.h>

// DirectNormLoss: B=16384 rows, D=2048 features, 1000 classes.
// loss = mean_i [ 1 - <s_i, c_i> / (||c_i|| * max(||s_i||, ||t_i||)) ]
//
// R9: R4 falsified the logical-byte-cap model (264MB vs 384MB, same time;
// one replay served ~0 bytes from HBM and STILL took 113us). The clean
// invariant across 10 variants: s/t's 256MB always streams at 2.3-2.4 TB/s
// (service-rate wall, Little's law -> queue-side tricks neutral). Copy
// bench read-rate ~3.15 TB/s => ~25% headroom, sole uneliminated suspect:
// every variant drains vmcnt->0 once per row (reduce consumes all loads).
// This round: wave/row structure, 2 rows/wave, straight-line ping-pong
// with sched_barrier(0) fence so ALL 48 loads issue before any consume
// (compiler then waits at vmcnt(24) for row A; row B stays in flight
// through A's reduce -> no per-row bubble). R6's lambda version collapsed
// (VGPR 76, scheduler sank issues); the fence makes that illegal.
// TELL: VGPR>=190 = pipeline real. Predict main 106->88-95us if bubble
// theory right; unchanged ~105 => service wall confirmed => ROOFLINE.

#define NROWS  16384
#define DDIM   2048
#define BLK    256
#define WPB    (BLK / 64)              // 4 waves per block
#define RPW    2                       // rows per wave (ping-pong)
#define GRID   (NROWS / (WPB * RPW))   // 2048 blocks -> 8192 waves
#define GRID_AT (NROWS / WPB)          // fallback grid (wave/row)

typedef float v4f __attribute__((ext_vector_type(4)));

__device__ __forceinline__ float dot4(const v4f a, const v4f b) {
    return a.x*b.x + a.y*b.y + a.z*b.z + a.w*b.w;
}

__global__ __launch_bounds__(BLK, 1) void dnl_main_kernel(
    const float* __restrict__ s_emb,
    const float* __restrict__ t_emb,
    const float* __restrict__ T_EMB,
    const int*   __restrict__ labels,
    float*       __restrict__ partial)   // [NROWS]
{
    const int tid  = threadIdx.x;
    const int lane = tid & 63;
    const int wave = blockIdx.x * WPB + (tid >> 6);   // wave-uniform
    const int rowA = wave * RPW;
    const int rowB = rowA + 1;

    const int labA = labels[rowA];
    const int labB = labels[rowB];

    const v4f* sA4 = (const v4f*)(s_emb + (size_t)rowA * DDIM);
    const v4f* tA4 = (const v4f*)(t_emb + (size_t)rowA * DDIM);
    const v4f* cA4 = (const v4f*)(T_EMB + (size_t)labA * DDIM);
    const v4f* sB4 = (const v4f*)(s_emb + (size_t)rowB * DDIM);
    const v4f* tB4 = (const v4f*)(t_emb + (size_t)rowB * DDIM);
    const v4f* cB4 = (const v4f*)(T_EMB + (size_t)labB * DDIM);

    // ---- issue phase: all 48 vector loads, no consumption ----
    v4f sA[8], tA[8], cA[8], sB[8], tB[8], cB[8];
    #pragma unroll
    for (int j = 0; j < 8; ++j) {
        const int k = lane + j * 64;
        sA[j] = sA4[k];
        tA[j] = tA4[k];
        cA[j] = cA4[k];
    }
    #pragma unroll
    for (int j = 0; j < 8; ++j) {
        const int k = lane + j * 64;
        sB[j] = sB4[k];
        tB[j] = tB4[k];
        cB[j] = cB4[k];
    }

    // Fence: nothing below may be hoisted above, nothing above may sink.
    // Forces both issue bursts to precede any consume, so A's consume
    // waits at vmcnt(24) while B's 24 loads remain in flight.
    __builtin_amdgcn_sched_barrier(0);

    // ---- consume A (B's loads still outstanding) ----
    {
        float ss = 0.f, tt = 0.f, sc = 0.f, cc = 0.f;
        #pragma unroll
        for (int j = 0; j < 8; ++j) {
            ss += dot4(sA[j], sA[j]);
            tt += dot4(tA[j], tA[j]);
            sc += dot4(sA[j], cA[j]);
            cc += dot4(cA[j], cA[j]);
        }
        #pragma unroll
        for (int off = 32; off > 0; off >>= 1) {
            ss += __shfl_xor(ss, off, 64);
            tt += __shfl_xor(tt, off, 64);
            sc += __shfl_xor(sc, off, 64);
            cc += __shfl_xor(cc, off, 64);
        }
        if (lane == 0) {
            const float max_norm = fmaxf(sqrtf(ss), sqrtf(tt));
            partial[rowA] = 1.0f - sc / (sqrtf(cc) * max_norm);
        }
    }

    // ---- consume B ----
    {
        float ss = 0.f, tt = 0.f, sc = 0.f, cc = 0.f;
        #pragma unroll
        for (int j = 0; j < 8; ++j) {
            ss += dot4(sB[j], sB[j]);
            tt += dot4(tB[j], tB[j]);
            sc += dot4(sB[j], cB[j]);
            cc += dot4(cB[j], cB[j]);
        }
        #pragma unroll
        for (int off = 32; off > 0; off >>= 1) {
            ss += __shfl_xor(ss, off, 64);
            tt += __shfl_xor(tt, off, 64);
            sc += __shfl_xor(sc, off, 64);
            cc += __shfl_xor(cc, off, 64);
        }
        if (lane == 0) {
            const float max_norm = fmaxf(sqrtf(ss), sqrtf(tt));
            partial[rowB] = 1.0f - sc / (sqrtf(cc) * max_norm);
        }
    }
}

__global__ __launch_bounds__(BLK) void dnl_reduce_kernel(
    const float* __restrict__ partial,
    float*       __restrict__ out)
{
    const int tid = threadIdx.x;
    const float4* p4 = (const float4*)partial;
    float sum = 0.f;
    #pragma unroll
    for (int j = 0; j < 16; ++j) {
        const float4 v = p4[tid + j * BLK];
        sum += v.x + v.y + v.z + v.w;
    }
    #pragma unroll
    for (int off = 32; off > 0; off >>= 1)
        sum += __shfl_xor(sum, off, 64);

    __shared__ float red[4];
    if ((tid & 63) == 0) red[tid >> 6] = sum;
    __syncthreads();
    if (tid == 0)
        out[0] = (red[0] + red[1] + red[2] + red[3]) * (1.0f / (float)NROWS);
}

// Atomic fallback (only if ws too small): wave/row, known-good path.
__global__ __launch_bounds__(BLK, 2) void dnl_main_atomic_kernel(
    const float* __restrict__ s_emb,
    const float* __restrict__ t_emb,
    const float* __restrict__ T_EMB,
    const int*   __restrict__ labels,
    float*       __restrict__ out)
{
    const int tid  = threadIdx.x;
    const int lane = tid & 63;
    const int row  = blockIdx.x * WPB + (tid >> 6);
    const int label = labels[row];

    const v4f* s4 = (const v4f*)(s_emb + (size_t)row   * DDIM);
    const v4f* t4 = (const v4f*)(t_emb + (size_t)row   * DDIM);
    const v4f* c4 = (const v4f*)(T_EMB + (size_t)label * DDIM);

    float ss = 0.f, tt = 0.f, sc = 0.f, cc = 0.f;
    #pragma unroll
    for (int j = 0; j < 8; ++j) {
        const int k = lane + j * 64;
        const v4f s = s4[k];
        const v4f t = t4[k];
        const v4f c = c4[k];
        ss += dot4(s, s);
        tt += dot4(t, t);
        sc += dot4(s, c);
        cc += dot4(c, c);
    }
    #pragma unroll
    for (int off = 32; off > 0; off >>= 1) {
        ss += __shfl_xor(ss, off, 64);
        tt += __shfl_xor(tt, off, 64);
        sc += __shfl_xor(sc, off, 64);
        cc += __shfl_xor(cc, off, 64);
    }
    if (lane == 0) {
        const float max_norm = fmaxf(sqrtf(ss), sqrtf(tt));
        atomicAdd(out, (1.0f - sc / (sqrtf(cc) * max_norm)) * (1.0f / (float)NROWS));
    }
}

extern "C" void kernel_launch(void* const* d_in, const int* in_sizes, int n_in,
                              void* d_out, int out_size, void* d_ws, size_t ws_size,
                              hipStream_t stream) {
    const float* s_emb  = (const float*)d_in[0];
    const float* t_emb  = (const float*)d_in[1];
    const float* T_EMB  = (const float*)d_in[2];
    const int*   labels = (const int*)d_in[3];
    float* out = (float*)d_out;

    if (ws_size >= (size_t)NROWS * sizeof(float)) {
        float* partial = (float*)d_ws;
        dnl_main_kernel<<<GRID, BLK, 0, stream>>>(s_emb, t_emb, T_EMB, labels, partial);
        dnl_reduce_kernel<<<1, BLK, 0, stream>>>(partial, out);
    } else {
        hipMemsetAsync(d_out, 0, sizeof(float), stream);
        dnl_main_atomic_kernel<<<GRID_AT, BLK, 0, stream>>>(s_emb, t_emb, T_EMB, labels, out);
    }
}